// Round 7
// baseline (1637.477 us; speedup 1.0000x reference)
//
#include <hip/hip_runtime.h>
#include <stdint.h>

// Fused 2-layer LSTM: B=2048, T=512, F=32, H=128, G=512.
// ROUND 7: 4 FAT WAVES (1 wave/SIMD, 512-reg budget), weights ~all in regs.
//  Counter-model revision (r6): VALUBusy INCLUDES MFMA cycles (v_mfma is
//  VALU-class; gfx94x derived formula). Every round: VALU/Mfma ~= 1.3 ->
//  non-MFMA VALU is only ~500 cyc/iter. Machine is ~57% busy, ~43% STALLED
//  (~2000 cyc/iter) -- matching the 176 ds_read_b128/CU/iter (~2100 cyc of
//  CU-shared LDS pipe) feeding MFMAs through lgkm waits at 2 waves/SIMD.
//  Fix: WG = 256 thr = 4 waves, __launch_bounds__(256,1) -> 1 wave/SIMD,
//  512 unified VGPR+AGPR budget. Each wave owns 32 h-cols of BOTH layers
//  (grp0: w*16..+16, grp1: +64): register-resident Whh0 (128 regs) + Whh1
//  (128) + Wih1 kc0,1 (64) = 320; streamed from per-wave slot-contiguous
//  conflict-free LDS images: Wih0 (8 reads/iter) + Wih1 kc2,3 (16, dbuf).
//  LDS traffic 176 -> 128 reads/CU/iter... -> 64 KB/CU/iter (~770 cyc),
//  well under the 2018-cyc matrix-pipe floor. MFMA/SIMD unchanged (104).
//  Skew (L0 step tau + L1 step tau-1, peeled prologue/epilogue), lgkm-only
//  barrier, log2-domain folded f16-packed biases kept from prior rounds.
//  Static live regs ~460 < 512 (m08: no spill through 450; spill shows as
//  WRITE_SIZE jump).

#define B_ 2048
#define T_ 512
#define F_ 32
#define H_ 128
#define LSTR 144                 // halves per h-buffer row (2-way banks: free)
#define H0SZ (8 * LSTR)          // halves per h buffer
#define W0WAVE 4096              // halves per wave: Wih0 image, 8 slots x 512
#define W1WAVE 8192              // halves per wave: Wih1 kc2,3 image, 16 slots

#define LOG2E 1.4426950408889634f

typedef _Float16 half8 __attribute__((ext_vector_type(8)));
typedef float float4_t __attribute__((ext_vector_type(4)));

// lgkm-only barrier: x prefetch (vmcnt) stays in flight; "memory" clobber
// stops hoisting of the per-iter image ds_reads (they must stay in-loop so
// the reg allocator doesn't promote the images to registers).
#define BARRIER_LGKM() asm volatile("s_waitcnt lgkmcnt(0)\n\ts_barrier" ::: "memory")

__device__ __forceinline__ float fexp2(float x) {
  float r; asm("v_exp_f32 %0, %1" : "=v"(r) : "v"(x)); return r;
}
__device__ __forceinline__ float frcp(float x) { return __builtin_amdgcn_rcpf(x); }

__device__ __forceinline__ half8 cvt2f4(float4_t a, float4_t b) {
  half8 r;
  r[0] = (_Float16)a[0]; r[1] = (_Float16)a[1]; r[2] = (_Float16)a[2]; r[3] = (_Float16)a[3];
  r[4] = (_Float16)b[0]; r[5] = (_Float16)b[1]; r[6] = (_Float16)b[2]; r[7] = (_Float16)b[3];
  return r;
}
__device__ __forceinline__ half8 load8cvt(const float* p) {
  return cvt2f4(*(const float4_t*)p, *(const float4_t*)(p + 4));
}

__global__ __launch_bounds__(256, 1) void lstm_fused(
    const float* __restrict__ x, const float* __restrict__ Wih0,
    const float* __restrict__ Whh0, const float* __restrict__ b0,
    const float* __restrict__ Wih1, const float* __restrict__ Whh1,
    const float* __restrict__ b1, const float* __restrict__ Wfc,
    const float* __restrict__ bfc, float* __restrict__ out)
{
  __shared__ __attribute__((aligned(16))) _Float16 lds_w0[4 * W0WAVE];  // 32 KB
  __shared__ __attribute__((aligned(16))) _Float16 lds_w1[4 * W1WAVE];  // 64 KB
  __shared__ __attribute__((aligned(16))) _Float16 lds_h0[2 * H0SZ];    // 4608 B
  __shared__ __attribute__((aligned(16))) _Float16 lds_h1[2 * H0SZ];    // 4608 B
  __shared__ float lds_fc[4][8];

  const int tid  = threadIdx.x;
  const int w    = tid >> 6;                // 0..3 (one wave per SIMD)
  const int lane = tid & 63;
  const int n    = lane & 15;
  const int q    = lane >> 4;
  const int rbase = (int)blockIdx.x * 8;
  const int rsh  = (q >> 1) * 2;            // acc rows this lane finalizes
  const int rowq = (q & 1) * 4;             // base output row
  const int hc0  = w * 16 + n;              // col-group 0 h-column
  const int hc1  = hc0 + 64;                // col-group 1 h-column
  const int aoff = (n & 7) * LSTR + q * 8;  // A-frag read offset (halves)

  // ---- setup: Whh0/Whh1/Wih1(kc0,1) -> regs; Wih0 + Wih1(kc2,3) -> LDS ----
  // Image slots: 512 halves (1 KB); lane (q,n) owns halves q*128+n*8 ->
  // each wave's ds_read_b128 of a slot covers 1024 contiguous bytes:
  // conflict-free (proven r2/r3: conflicts 7.55e7 -> 8.4e6).
  half8 bwhh0[2][4][4], bwhh1[2][4][4], bwih1r[2][2][4];   // 320 regs
  _Float16* w0base = lds_w0 + w * W0WAVE + q * 128 + n * 8;
  _Float16* w1base = lds_w1 + w * W1WAVE + q * 128 + n * 8;
  half8 cpk0, cpk1;     // f16-packed folded biases [grp0:I,F,G,O, grp1:I,F,G,O]
#pragma unroll
  for (int grp = 0; grp < 2; ++grp) {
    const int hcol = grp ? hc1 : hc0;
#pragma unroll
    for (int gt = 0; gt < 4; ++gt) {
      const int g = gt * H_ + hcol;
      *(half8*)(w0base + (grp * 4 + gt) * 512) = load8cvt(Wih0 + g * F_ + q * 8);
#pragma unroll
      for (int kc = 0; kc < 4; ++kc) {
        bwhh0[grp][gt][kc] = load8cvt(Whh0 + g * H_ + kc * 32 + q * 8);
        bwhh1[grp][gt][kc] = load8cvt(Whh1 + g * H_ + kc * 32 + q * 8);
      }
      bwih1r[grp][0][gt] = load8cvt(Wih1 + g * H_ + 0 * 32 + q * 8);
      bwih1r[grp][1][gt] = load8cvt(Wih1 + g * H_ + 1 * 32 + q * 8);
      *(half8*)(w1base + (grp * 8 + gt) * 512)     = load8cvt(Wih1 + g * H_ + 2 * 32 + q * 8);
      *(half8*)(w1base + (grp * 8 + 4 + gt) * 512) = load8cvt(Wih1 + g * H_ + 3 * 32 + q * 8);
    }
    cpk0[grp * 4 + 0] = (_Float16)(-b0[0 * H_ + hcol] * LOG2E);
    cpk0[grp * 4 + 1] = (_Float16)(-b0[1 * H_ + hcol] * LOG2E);
    cpk0[grp * 4 + 2] = (_Float16)( b0[2 * H_ + hcol] * (2.0f * LOG2E));
    cpk0[grp * 4 + 3] = (_Float16)(-b0[3 * H_ + hcol] * LOG2E);
    cpk1[grp * 4 + 0] = (_Float16)(-b1[0 * H_ + hcol] * LOG2E);
    cpk1[grp * 4 + 1] = (_Float16)(-b1[1 * H_ + hcol] * LOG2E);
    cpk1[grp * 4 + 2] = (_Float16)( b1[2 * H_ + hcol] * (2.0f * LOG2E));
    cpk1[grp * 4 + 3] = (_Float16)(-b1[3 * H_ + hcol] * LOG2E);
  }

  // h1(-1) must read as 0 at tau=1 (buf1); zero both h1 buffers. h0 needs no
  // zeroing (prologue fully writes buf0 before any read).
  for (int i = tid; i < 2 * H0SZ; i += 256) lds_h1[i] = (_Float16)0.0f;
  __syncthreads();   // setup writes (incl. own images) visible

  const float4_t zC = {0.f, 0.f, 0.f, 0.f};
  float c0a[2] = {0.f, 0.f}, c0b[2] = {0.f, 0.f};   // layer-0 cell state
  float c1a[2] = {0.f, 0.f}, c1b[2] = {0.f, 0.f};   // layer-1 cell state

  const float* xptr = x + (rbase + (n & 7)) * (T_ * F_) + q * 8;
  float4_t xrA = *(const float4_t*)(xptr);
  float4_t xrB = *(const float4_t*)(xptr + 4);

  // gate evaluator: 2 rows, log2-domain folded biases (f16-packed), h -> f16
  auto GATES = [&](const float4_t (&acc)[4], half8 cpk, int grp, float& ca,
                   float& cb, _Float16* dst, int hcol) {
    const float cI = (float)cpk[grp * 4 + 0];
    const float cF = (float)cpk[grp * 4 + 1];
    const float cG = (float)cpk[grp * 4 + 2];
    const float cO = (float)cpk[grp * 4 + 3];
#pragma unroll
    for (int rr = 0; rr < 2; ++rr) {
      const int ri = rsh + rr;
      const float gi = frcp(1.0f + fexp2(__builtin_fmaf(acc[0][ri], -LOG2E, cI)));
      const float gf = frcp(1.0f + fexp2(__builtin_fmaf(acc[1][ri], -LOG2E, cF)));
      const float gg = 1.0f - 2.0f * frcp(1.0f + fexp2(__builtin_fmaf(acc[2][ri], 2.0f * LOG2E, cG)));
      const float go = frcp(1.0f + fexp2(__builtin_fmaf(acc[3][ri], -LOG2E, cO)));
      float& cc = rr ? cb : ca;
      cc = __builtin_fmaf(gf, cc, gi * gg);
      const float th = 1.0f - 2.0f * frcp(1.0f + fexp2(cc * (2.0f * LOG2E)));
      dst[(rowq + ri) * LSTR + hcol] = (_Float16)(go * th);
    }
  };

  // layer-1 step: ih kc0,1 from regs; kc2,3 from LDS image (dbuf windows);
  // hh from regs. ah = h0 A-frags already in regs from the L0 phase.
  auto L1STEP = [&](const half8 (&ah)[4], _Float16* h1rd, _Float16* h1wr) {
    half8 a1h[4];
#pragma unroll
    for (int kc = 0; kc < 4; ++kc)
      a1h[kc] = *(const half8*)(h1rd + aoff + kc * 32);
#pragma unroll
    for (int grp = 0; grp < 2; ++grp) {
      half8 wA[4], wB[4];
      float4_t acc[4];
#pragma unroll
      for (int gt = 0; gt < 4; ++gt)      // issue kc2 stream early
        wA[gt] = *(const half8*)(w1base + (grp * 8 + gt) * 512);
#pragma unroll
      for (int gt = 0; gt < 4; ++gt)      // ih kc=0 (regs)
        acc[gt] = __builtin_amdgcn_mfma_f32_16x16x32_f16(ah[0], bwih1r[grp][0][gt], zC, 0, 0, 0);
#pragma unroll
      for (int gt = 0; gt < 4; ++gt)      // ih kc=1 (regs)
        acc[gt] = __builtin_amdgcn_mfma_f32_16x16x32_f16(ah[1], bwih1r[grp][1][gt], acc[gt], 0, 0, 0);
#pragma unroll
      for (int gt = 0; gt < 4; ++gt)      // issue kc3 stream
        wB[gt] = *(const half8*)(w1base + (grp * 8 + 4 + gt) * 512);
#pragma unroll
      for (int gt = 0; gt < 4; ++gt)      // ih kc=2 (streamed)
        acc[gt] = __builtin_amdgcn_mfma_f32_16x16x32_f16(ah[2], wA[gt], acc[gt], 0, 0, 0);
#pragma unroll
      for (int gt = 0; gt < 4; ++gt)      // ih kc=3 (streamed)
        acc[gt] = __builtin_amdgcn_mfma_f32_16x16x32_f16(ah[3], wB[gt], acc[gt], 0, 0, 0);
#pragma unroll
      for (int kc = 0; kc < 4; ++kc)      // hh (regs)
#pragma unroll
        for (int gt = 0; gt < 4; ++gt)
          acc[gt] = __builtin_amdgcn_mfma_f32_16x16x32_f16(a1h[kc], bwhh1[grp][gt][kc], acc[gt], 0, 0, 0);
      GATES(acc, cpk1, grp, c1a[grp], c1b[grp], h1wr, grp ? hc1 : hc0);
    }
  };

  // ---- prologue tau=0: layer-0 ih only (h_-1 = 0) ----
  {
    half8 w0w[4];
#pragma unroll
    for (int gt = 0; gt < 4; ++gt)
      w0w[gt] = *(const half8*)(w0base + gt * 512);
    half8 ax = cvt2f4(xrA, xrB);
#pragma unroll
    for (int grp = 0; grp < 2; ++grp) {
      float4_t acc[4];
#pragma unroll
      for (int gt = 0; gt < 4; ++gt)
        acc[gt] = __builtin_amdgcn_mfma_f32_16x16x32_f16(ax, w0w[gt], zC, 0, 0, 0);
      if (grp == 0) {
#pragma unroll
        for (int gt = 0; gt < 4; ++gt)    // reuse window for grp1
          w0w[gt] = *(const half8*)(w0base + (4 + gt) * 512);
      }
      GATES(acc, cpk0, grp, c0a[grp], c0b[grp], lds_h0 /*buf0*/, grp ? hc1 : hc0);
    }
    xrA = *(const float4_t*)(xptr + F_);
    xrB = *(const float4_t*)(xptr + F_ + 4);
    BARRIER_LGKM();
  }

  // ---- main loop tau = 1..T_-1: L0 step tau + L1 step tau-1 ----
#pragma unroll 1
  for (int tau = 1; tau < T_; ++tau) {
    const int pw = tau & 1;
    _Float16* h0rd = lds_h0 + (pw ^ 1) * H0SZ;   // h0(tau-1)
    _Float16* h0wr = lds_h0 + pw * H0SZ;         // h0(tau)
    _Float16* h1rd = lds_h1 + pw * H0SZ;         // h1(tau-2)
    _Float16* h1wr = lds_h1 + (pw ^ 1) * H0SZ;   // h1(tau-1)

    half8 ah[4];                                  // h0(tau-1) A-frags
#pragma unroll
    for (int kc = 0; kc < 4; ++kc)
      ah[kc] = *(const half8*)(h0rd + aoff + kc * 32);
    half8 w0w[4];
#pragma unroll
    for (int gt = 0; gt < 4; ++gt)
      w0w[gt] = *(const half8*)(w0base + gt * 512);
    half8 ax = cvt2f4(xrA, xrB);

    // layer 0, step tau (grp-sequential; grp1 stream issued under grp0 work)
#pragma unroll
    for (int grp = 0; grp < 2; ++grp) {
      float4_t acc[4];
#pragma unroll
      for (int gt = 0; gt < 4; ++gt)
        acc[gt] = __builtin_amdgcn_mfma_f32_16x16x32_f16(ax, w0w[gt], zC, 0, 0, 0);
#pragma unroll
      for (int kc = 0; kc < 4; ++kc)
#pragma unroll
        for (int gt = 0; gt < 4; ++gt)
          acc[gt] = __builtin_amdgcn_mfma_f32_16x16x32_f16(ah[kc], bwhh0[grp][gt][kc], acc[gt], 0, 0, 0);
      if (grp == 0) {
#pragma unroll
        for (int gt = 0; gt < 4; ++gt)
          w0w[gt] = *(const half8*)(w0base + (4 + gt) * 512);
        const int tn = (tau + 1 < T_) ? tau + 1 : T_ - 1;   // x prefetch
        xrA = *(const float4_t*)(xptr + tn * F_);
        xrB = *(const float4_t*)(xptr + tn * F_ + 4);
      }
      GATES(acc, cpk0, grp, c0a[grp], c0b[grp], h0wr, grp ? hc1 : hc0);
    }

    // layer 1, step tau-1 (ah still live as shared A-frags)
    L1STEP(ah, h1rd, h1wr);
    BARRIER_LGKM();
  }

  // ---- epilogue: layer-1 step T_-1 ----
  {
    _Float16* h0rd = lds_h0 + H0SZ;   // h0(T_-1): tau=T_-1 (pw=1) wrote buf1
    _Float16* h1rd = lds_h1;          // h1(T_-2): tau=T_-1 wrote buf0
    _Float16* h1wr = lds_h1 + H0SZ;   // h1(T_-1) -> buf1 (FC reads here)
    half8 ah[4];
#pragma unroll
    for (int kc = 0; kc < 4; ++kc)
      ah[kc] = *(const half8*)(h0rd + aoff + kc * 32);
    L1STEP(ah, h1rd, h1wr);
  }
  __syncthreads();   // h1(T_-1) visible to all waves

  // ---- FC head: out[row] = sum_c h1_last[row][c]*Wfc[c] + bfc ----
  // wave w covers cols hc0, hc1; rows q (p0) and q+4 (p1).
  const float wf0 = Wfc[hc0], wf1 = Wfc[hc1];
  float p0 = (float)lds_h1[H0SZ + q * LSTR + hc0] * wf0
           + (float)lds_h1[H0SZ + q * LSTR + hc1] * wf1;
  float p1 = (float)lds_h1[H0SZ + (q + 4) * LSTR + hc0] * wf0
           + (float)lds_h1[H0SZ + (q + 4) * LSTR + hc1] * wf1;
#pragma unroll
  for (int m = 1; m < 16; m <<= 1) {
    p0 += __shfl_xor(p0, m);
    p1 += __shfl_xor(p1, m);
  }
  if (n == 0) {
    lds_fc[w][q] = p0;
    lds_fc[w][q + 4] = p1;
  }
  __syncthreads();
  if (tid < 8) {
    float s = bfc[0];
#pragma unroll
    for (int wv = 0; wv < 4; ++wv) s += lds_fc[wv][tid];
    out[rbase + tid] = s;
  }
}

extern "C" void kernel_launch(void* const* d_in, const int* in_sizes, int n_in,
                              void* d_out, int out_size, void* d_ws, size_t ws_size,
                              hipStream_t stream) {
  const float* x    = (const float*)d_in[0];
  const float* Wih0 = (const float*)d_in[1];
  const float* Whh0 = (const float*)d_in[2];
  const float* b0   = (const float*)d_in[3];
  const float* Wih1 = (const float*)d_in[4];
  const float* Whh1 = (const float*)d_in[5];
  const float* b1   = (const float*)d_in[6];
  const float* Wfc  = (const float*)d_in[7];
  const float* bfc  = (const float*)d_in[8];
  float* outp = (float*)d_out;
  (void)d_ws; (void)ws_size;

  lstm_fused<<<B_ / 8, 256, 0, stream>>>(x, Wih0, Whh0, b0, Wih1, Whh1, b1,
                                         Wfc, bfc, outp);
}

// Round 8
// 1127.998 us; speedup vs baseline: 1.4517x; 1.4517x over previous
//
#include <hip/hip_runtime.h>
#include <stdint.h>

// Fused 2-layer LSTM: B=2048, T=512, F=32, H=128, G=512. One WG (512 thr,
// 8 waves) per 8 batch rows; 256 WGs = 1/CU. Skewed schedule: iteration tau
// runs layer-0 step tau AND layer-1 step tau-1 (round-4 uniform structure —
// role-split (r5/r6) and fat-wave (r7) both falsified).
// ROUND 8: HYBRID Wih1 STREAM, ISSUED CROSS-BARRIER.
//  Pipe model (r3-r7 counters): matrix 2018 cyc/SIMD + ~500 VALU + LDS pipe
//  ~1500-2100 cyc/CU (176 ds_read_b128/iter) + barrier tails ~= the SUM:
//  everything serializes through the lgkm waits + lockstep barrier.
//  Fix: Wih1 kc0,1 fragments move to a fragment-ordered f16 image in d_ws
//  (64 KB, written redundantly by every WG at setup -- identical values,
//  race-benign; L2-resident: ALL WGs read the SAME image). In-loop they are
//  GLOBAL loads whose vmcnt survives the lgkm-only barrier -> issued one
//  full iteration ahead (vmcnt retires in order, so these older loads never
//  wait on the younger x prefetch). Wih1 kc2,3 stay in a 64 KB LDS image
//  (slot-contiguous, conflict-free) read with >=200 cyc lead. LDS traffic
//  176 -> 128 reads/iter; L2 adds 64 KB/iter/CU (~1.7 TB/s per XCD, well
//  under ceiling) on an independent pipe.
//  Register budget at 2 waves/SIMD (r2/r7 proved exceeding it spills):
//  cached Wih0(16)+Whh0(64)+Whh1(64)=144; windows staged so wA/wB die
//  before wC/wD peak; acc0 dead before acc1 born -> peak ~244 < 253.
//  Fallback template (ws too small) = round-4 all-LDS behavior.

#define B_ 2048
#define T_ 512
#define F_ 32
#define H_ 128
#define LSTR 144                 // halves per h-buffer row
#define H0SZ (8 * LSTR)          // halves per h buffer

#define LOG2E 1.4426950408889634f

typedef _Float16 half8 __attribute__((ext_vector_type(8)));
typedef float float4_t __attribute__((ext_vector_type(4)));

// lgkm-only barrier: vmcnt (x prefetch + cross-iter weight loads) stays in
// flight across it. "memory" clobber pins issue order and keeps the per-iter
// image reads in-loop.
#define BARRIER_LGKM() asm volatile("s_waitcnt lgkmcnt(0)\n\ts_barrier" ::: "memory")

__device__ __forceinline__ float fexp2(float x) {
  float r; asm("v_exp_f32 %0, %1" : "=v"(r) : "v"(x)); return r;
}
__device__ __forceinline__ float frcp(float x) { return __builtin_amdgcn_rcpf(x); }

__device__ __forceinline__ half8 cvt2f4(float4_t a, float4_t b) {
  half8 r;
  r[0] = (_Float16)a[0]; r[1] = (_Float16)a[1]; r[2] = (_Float16)a[2]; r[3] = (_Float16)a[3];
  r[4] = (_Float16)b[0]; r[5] = (_Float16)b[1]; r[6] = (_Float16)b[2]; r[7] = (_Float16)b[3];
  return r;
}
__device__ __forceinline__ half8 load8cvt(const float* p) {
  return cvt2f4(*(const float4_t*)p, *(const float4_t*)(p + 4));
}

// WS=true: Wih1 kc0,1 streamed from d_ws image (global/L2, cross-barrier
// vmcnt), kc2,3 from 64 KB LDS image. WS=false: round-4 all-LDS (128 KB).
template <bool WS>
__global__ __launch_bounds__(512, 2) void lstm_fused(
    const float* __restrict__ x, const float* __restrict__ Wih0,
    const float* __restrict__ Whh0, const float* __restrict__ b0,
    const float* __restrict__ Wih1, const float* __restrict__ Whh1,
    const float* __restrict__ b1, const float* __restrict__ Wfc,
    const float* __restrict__ bfc, _Float16* __restrict__ wimg,
    float* __restrict__ out)
{
  // WS: 8 slots/wave (kc2,3) + 4096-halves pad (keeps LDS > 80 KB so at most
  // one WG/CU even if the dispatcher would pack). !WS: 16 slots/wave.
  constexpr int W1SLOTS = WS ? 8 : 16;
  constexpr int W1WAVE  = W1SLOTS * 512;
  __shared__ __attribute__((aligned(16))) _Float16 lds_w1[8 * W1WAVE + (WS ? 4096 : 0)];
  __shared__ __attribute__((aligned(16))) _Float16 lds_h0[2 * H0SZ];   // 4608 B
  __shared__ __attribute__((aligned(16))) _Float16 lds_h1[2 * H0SZ];   // 4608 B
  __shared__ float lds_fc[8][8];

  const int tid  = threadIdx.x;
  const int w    = tid >> 6;
  const int lane = tid & 63;
  const int n    = lane & 15;
  const int q    = lane >> 4;
  const int rbase = (int)blockIdx.x * 8;
  const int rsh  = (q >> 1) * 2;            // acc rows this lane finalizes
  const int rowq = (q & 1) * 4;             // base output row
  const int colg = w * 16 + n;              // this lane's h-column
  const int aoff = (n & 7) * LSTR + q * 8;  // A-frag read offset (halves)

  // ---- setup: Wih0/Whh0/Whh1 -> regs; Wih1 -> ws image (kc0,1) + LDS ----
  // LDS image: per-wave slot stride 512 halves; lane (q,n) owns q*128+n*8 ->
  // each wave ds_read_b128 covers 1024 contiguous B: conflict-free (r2/r3).
  // ws image: frag fi=((w*4+j)*2+kcp), lane slot = fi*64+lane half8s; one
  // global_load_dwordx4 per frag per lane. All WGs write identical bytes.
  half8 bwih0[4], bwhh0[4][4], bwhh1[4][4];
  _Float16* w1base = lds_w1 + w * W1WAVE + q * 128 + n * 8;
  half8* wsw = (half8*)wimg + lane;
  const half8* wsp = (const half8*)wimg + lane;
#pragma unroll
  for (int j = 0; j < 4; ++j) {
    const int g = j * H_ + colg;            // == (j*8+w)*16+n
    bwih0[j] = load8cvt(Wih0 + g * F_ + q * 8);
#pragma unroll
    for (int kc = 0; kc < 4; ++kc) {
      bwhh0[j][kc] = load8cvt(Whh0 + g * H_ + kc * 32 + q * 8);
      bwhh1[j][kc] = load8cvt(Whh1 + g * H_ + kc * 32 + q * 8);
    }
    if constexpr (WS) {
      wsw[(((w << 2) + j) * 2 + 0) * 64] = load8cvt(Wih1 + g * H_ + 0 * 32 + q * 8);
      wsw[(((w << 2) + j) * 2 + 1) * 64] = load8cvt(Wih1 + g * H_ + 1 * 32 + q * 8);
      *(half8*)(w1base + (0 * 4 + j) * 512) = load8cvt(Wih1 + g * H_ + 2 * 32 + q * 8);
      *(half8*)(w1base + (1 * 4 + j) * 512) = load8cvt(Wih1 + g * H_ + 3 * 32 + q * 8);
    } else {
#pragma unroll
      for (int kc = 0; kc < 4; ++kc)
        *(half8*)(w1base + (kc * 4 + j) * 512) = load8cvt(Wih1 + g * H_ + kc * 32 + q * 8);
    }
  }
  // folded gate biases (log2 domain)
  const float cI0 = -b0[0 * H_ + colg] * LOG2E;
  const float cF0 = -b0[1 * H_ + colg] * LOG2E;
  const float cG0 =  b0[2 * H_ + colg] * (2.0f * LOG2E);
  const float cO0 = -b0[3 * H_ + colg] * LOG2E;
  const float cI1 = -b1[0 * H_ + colg] * LOG2E;
  const float cF1 = -b1[1 * H_ + colg] * LOG2E;
  const float cG1 =  b1[2 * H_ + colg] * (2.0f * LOG2E);
  const float cO1 = -b1[3 * H_ + colg] * LOG2E;

  // h1(-1) must read 0 at tau=1; h0 buf0 fully written by prologue.
  for (int i = tid; i < 2 * H0SZ; i += 512) lds_h1[i] = (_Float16)0.0f;
  __syncthreads();   // drains vmcnt too -> own ws-image writes visible

  const float4_t zC = {0.f, 0.f, 0.f, 0.f};
  float c00 = 0.f, c01 = 0.f;      // layer-0 cell state (2 rows)
  float c10 = 0.f, c11 = 0.f;      // layer-1 cell state

  const float* xptr = x + (rbase + (n & 7)) * (T_ * F_) + q * 8;
  float4_t xrA = *(const float4_t*)(xptr);
  float4_t xrB = *(const float4_t*)(xptr + 4);

  auto GATES = [&](const float4_t (&acc)[4], float cI, float cF, float cG,
                   float cO, float& ca, float& cb, _Float16* dst) {
#pragma unroll
    for (int rr = 0; rr < 2; ++rr) {
      const int ri = rsh + rr;
      const float gi = frcp(1.0f + fexp2(__builtin_fmaf(acc[0][ri], -LOG2E, cI)));
      const float gf = frcp(1.0f + fexp2(__builtin_fmaf(acc[1][ri], -LOG2E, cF)));
      const float gg = 1.0f - 2.0f * frcp(1.0f + fexp2(__builtin_fmaf(acc[2][ri], 2.0f * LOG2E, cG)));
      const float go = frcp(1.0f + fexp2(__builtin_fmaf(acc[3][ri], -LOG2E, cO)));
      float& cc = rr ? cb : ca;
      cc = __builtin_fmaf(gf, cc, gi * gg);
      const float th = 1.0f - 2.0f * frcp(1.0f + fexp2(cc * (2.0f * LOG2E)));
      dst[(rowq + ri) * LSTR + colg] = (_Float16)(go * th);
    }
  };

  half8 wA[4], wB[4];   // Wih1 kc0,1 windows: WS -> loop-carried (global,
                        // in flight across the barrier); !WS -> per-iter LDS

  // ---- peel tau=0: layer-0 ih only (h_-1 = 0); issue first kc0,1 ----
  {
    float4_t acc0[4];
    half8 ax = cvt2f4(xrA, xrB);
#pragma unroll
    for (int j = 0; j < 4; ++j)
      acc0[j] = __builtin_amdgcn_mfma_f32_16x16x32_f16(ax, bwih0[j], zC, 0, 0, 0);
    xrA = *(const float4_t*)(xptr + F_);            // prefetch x(1)
    xrB = *(const float4_t*)(xptr + F_ + 4);
    GATES(acc0, cI0, cF0, cG0, cO0, c00, c01, lds_h0 /* pw=0 buf */);
    if constexpr (WS) {
#pragma unroll
      for (int j = 0; j < 4; ++j) {
        wA[j] = wsp[(((w << 2) + j) * 2 + 0) * 64];
        wB[j] = wsp[(((w << 2) + j) * 2 + 1) * 64];
      }
    }
    BARRIER_LGKM();
  }

  // ---- main loop tau = 1..T_-1: straight-line ----
#pragma unroll 1
  for (int tau = 1; tau < T_; ++tau) {
    const int pw = tau & 1;
    _Float16* h0rd = lds_h0 + (pw ^ 1) * H0SZ;   // h0(tau-1)
    _Float16* h0wr = lds_h0 + pw * H0SZ;         // h0(tau)
    _Float16* h1rd = lds_h1 + pw * H0SZ;         // h1(tau-2)
    _Float16* h1wr = lds_h1 + (pw ^ 1) * H0SZ;   // h1(tau-1)

    half8 ah[4];                                  // h0(tau-1): shared A-frag
#pragma unroll
    for (int kc = 0; kc < 4; ++kc)
      ah[kc] = *(const half8*)(h0rd + aoff + kc * 32);
    half8 ax = cvt2f4(xrA, xrB);

    // layer 0, step tau
    float4_t acc0[4];
#pragma unroll
    for (int j = 0; j < 4; ++j)
      acc0[j] = __builtin_amdgcn_mfma_f32_16x16x32_f16(ax, bwih0[j], zC, 0, 0, 0);
#pragma unroll
    for (int kc = 0; kc < 4; ++kc)
#pragma unroll
      for (int j = 0; j < 4; ++j)
        acc0[j] = __builtin_amdgcn_mfma_f32_16x16x32_f16(ah[kc], bwhh0[j][kc], acc0[j], 0, 0, 0);
    const int tn = (tau + 1 < T_) ? tau + 1 : T_ - 1;     // x prefetch
    xrA = *(const float4_t*)(xptr + tn * F_);
    xrB = *(const float4_t*)(xptr + tn * F_ + 4);
    GATES(acc0, cI0, cF0, cG0, cO0, c00, c01, h0wr);      // acc0 dies

    // layer 1, step tau-1
    float4_t acc1[4];
    if constexpr (!WS) {                        // per-iter LDS kc0,1
#pragma unroll
      for (int j = 0; j < 4; ++j) wA[j] = *(const half8*)(w1base + (0 * 4 + j) * 512);
#pragma unroll
      for (int j = 0; j < 4; ++j) wB[j] = *(const half8*)(w1base + (1 * 4 + j) * 512);
    }
#pragma unroll
    for (int j = 0; j < 4; ++j)                 // ih kc=0 (wA dies)
      acc1[j] = __builtin_amdgcn_mfma_f32_16x16x32_f16(ah[0], wA[j], zC, 0, 0, 0);
    half8 wC[4], wD[4];                         // kc2,3 from LDS (staged)
#pragma unroll
    for (int j = 0; j < 4; ++j)
      wC[j] = *(const half8*)(w1base + ((WS ? 0 : 2) * 4 + j) * 512);
#pragma unroll
    for (int j = 0; j < 4; ++j)                 // ih kc=1 (wB dies)
      acc1[j] = __builtin_amdgcn_mfma_f32_16x16x32_f16(ah[1], wB[j], acc1[j], 0, 0, 0);
#pragma unroll
    for (int j = 0; j < 4; ++j)
      wD[j] = *(const half8*)(w1base + ((WS ? 1 : 3) * 4 + j) * 512);
    half8 a1h[4];                               // h1(tau-2)
#pragma unroll
    for (int kc = 0; kc < 4; ++kc)
      a1h[kc] = *(const half8*)(h1rd + aoff + kc * 32);
#pragma unroll
    for (int j = 0; j < 4; ++j)                 // ih kc=2
      acc1[j] = __builtin_amdgcn_mfma_f32_16x16x32_f16(ah[2], wC[j], acc1[j], 0, 0, 0);
#pragma unroll
    for (int j = 0; j < 4; ++j)                 // ih kc=3
      acc1[j] = __builtin_amdgcn_mfma_f32_16x16x32_f16(ah[3], wD[j], acc1[j], 0, 0, 0);
#pragma unroll
    for (int kc = 0; kc < 4; ++kc)              // hh (register-resident B)
#pragma unroll
      for (int j = 0; j < 4; ++j)
        acc1[j] = __builtin_amdgcn_mfma_f32_16x16x32_f16(a1h[kc], bwhh1[j][kc], acc1[j], 0, 0, 0);
    if constexpr (WS) {                         // issue NEXT iter kc0,1 (L2);
#pragma unroll                                  //  vmcnt rides across barrier
      for (int j = 0; j < 4; ++j) {
        wA[j] = wsp[(((w << 2) + j) * 2 + 0) * 64];
        wB[j] = wsp[(((w << 2) + j) * 2 + 1) * 64];
      }
    }
    GATES(acc1, cI1, cF1, cG1, cO1, c10, c11, h1wr);
    BARRIER_LGKM();
  }

  // ---- peel tau=T_: layer-1 step T_-1 only ----
  {
    _Float16* h0rd = lds_h0 + H0SZ;   // h0(T_-1): tau=T_-1 (pw=1) wrote buf1
    _Float16* h1rd = lds_h1;          // h1(T_-2): tau=T_-1 wrote buf0
    _Float16* h1wr = lds_h1 + H0SZ;   // h1(T_-1) -> buf1 (FC reads here)

    half8 ah[4], a1h[4];
#pragma unroll
    for (int kc = 0; kc < 4; ++kc) {
      ah[kc]  = *(const half8*)(h0rd + aoff + kc * 32);
      a1h[kc] = *(const half8*)(h1rd + aoff + kc * 32);
    }
    float4_t acc1[4];
    if constexpr (!WS) {
#pragma unroll
      for (int j = 0; j < 4; ++j) wA[j] = *(const half8*)(w1base + (0 * 4 + j) * 512);
#pragma unroll
      for (int j = 0; j < 4; ++j) wB[j] = *(const half8*)(w1base + (1 * 4 + j) * 512);
    }
#pragma unroll
    for (int j = 0; j < 4; ++j)
      acc1[j] = __builtin_amdgcn_mfma_f32_16x16x32_f16(ah[0], wA[j], zC, 0, 0, 0);
    half8 wC[4], wD[4];
#pragma unroll
    for (int j = 0; j < 4; ++j)
      wC[j] = *(const half8*)(w1base + ((WS ? 0 : 2) * 4 + j) * 512);
#pragma unroll
    for (int j = 0; j < 4; ++j)
      acc1[j] = __builtin_amdgcn_mfma_f32_16x16x32_f16(ah[1], wB[j], acc1[j], 0, 0, 0);
#pragma unroll
    for (int j = 0; j < 4; ++j)
      wD[j] = *(const half8*)(w1base + ((WS ? 1 : 3) * 4 + j) * 512);
#pragma unroll
    for (int j = 0; j < 4; ++j)
      acc1[j] = __builtin_amdgcn_mfma_f32_16x16x32_f16(ah[2], wC[j], acc1[j], 0, 0, 0);
#pragma unroll
    for (int j = 0; j < 4; ++j)
      acc1[j] = __builtin_amdgcn_mfma_f32_16x16x32_f16(ah[3], wD[j], acc1[j], 0, 0, 0);
#pragma unroll
    for (int kc = 0; kc < 4; ++kc)
#pragma unroll
      for (int j = 0; j < 4; ++j)
        acc1[j] = __builtin_amdgcn_mfma_f32_16x16x32_f16(a1h[kc], bwhh1[j][kc], acc1[j], 0, 0, 0);
    GATES(acc1, cI1, cF1, cG1, cO1, c10, c11, h1wr);
    asm volatile("s_waitcnt lgkmcnt(0)" ::: "memory");   // own writes visible
  }
  __syncthreads();   // h1(T_-1) visible to all waves

  // ---- FC head: out[row] = sum_c h1_last[row][c]*Wfc[c] + bfc ----
  const float wfcv = Wfc[colg];
  float p0 = (float)lds_h1[H0SZ + (rowq + rsh + 0) * LSTR + colg] * wfcv;
  float p1 = (float)lds_h1[H0SZ + (rowq + rsh + 1) * LSTR + colg] * wfcv;
#pragma unroll
  for (int m = 1; m < 16; m <<= 1) {
    p0 += __shfl_xor(p0, m);
    p1 += __shfl_xor(p1, m);
  }
  if (n == 0) {
    lds_fc[w][rowq + rsh + 0] = p0;
    lds_fc[w][rowq + rsh + 1] = p1;
  }
  __syncthreads();
  if (tid < 8) {
    float s = bfc[0];
#pragma unroll
    for (int wv = 0; wv < 8; ++wv) s += lds_fc[wv][tid];
    out[rbase + tid] = s;
  }
}

extern "C" void kernel_launch(void* const* d_in, const int* in_sizes, int n_in,
                              void* d_out, int out_size, void* d_ws, size_t ws_size,
                              hipStream_t stream) {
  const float* x    = (const float*)d_in[0];
  const float* Wih0 = (const float*)d_in[1];
  const float* Whh0 = (const float*)d_in[2];
  const float* b0   = (const float*)d_in[3];
  const float* Wih1 = (const float*)d_in[4];
  const float* Whh1 = (const float*)d_in[5];
  const float* b1   = (const float*)d_in[6];
  const float* Wfc  = (const float*)d_in[7];
  const float* bfc  = (const float*)d_in[8];
  float* outp = (float*)d_out;
  (void)in_sizes; (void)n_in; (void)out_size;

  if (d_ws != nullptr && ws_size >= 65536) {
    lstm_fused<true><<<B_ / 8, 512, 0, stream>>>(x, Wih0, Whh0, b0, Wih1, Whh1,
                                                 b1, Wfc, bfc, (_Float16*)d_ws,
                                                 outp);
  } else {
    lstm_fused<false><<<B_ / 8, 512, 0, stream>>>(x, Wih0, Whh0, b0, Wih1, Whh1,
                                                  b1, Wfc, bfc, (_Float16*)nullptr,
                                                  outp);
  }
}

// Round 9
// 1023.509 us; speedup vs baseline: 1.5999x; 1.1021x over previous
//
#include <hip/hip_runtime.h>
#include <stdint.h>

// Fused 2-layer LSTM: B=2048, T=512, F=32, H=128, G=512. One WG (512 thr,
// 8 waves) per 8 batch rows; 256 WGs = 1/CU. Skewed schedule: iteration tau
// runs layer-0 step tau AND layer-1 step tau-1. Base = round 4 (best, 953us).
// ROUND 9: PHASE-REORDER BY WAVE PARITY.
//  CU pipe model (r3-r8): DS-unit ~2100 cyc/iter (176 ds_read_b128) +
//  matrix ~2020 cyc + VALU ~500 ~= measured 4480: DS and matrix fully
//  SERIALIZE because all waves march through identical phases in lockstep
//  between shared barriers (when one wave stalls on its L1 weight-stream
//  lgkm, its SIMD partner is stalled on the same phase's stream).
//  Fix: even waves execute L0-section then L1-section; odd waves L1 then
//  L0. Both legal (L1 step tau-1 reads only h0(tau-1), h1(tau-2) -- both
//  pre-barrier) and identical in work/reads/writes/barriers -> no load
//  imbalance (r5/r6's flaw). At any instant half the CU's waves are in the
//  DS-heavy L1 stream while the other half run reg-fed L0 MFMAs/gates, so
//  DS bursts overlay matrix/VALU phases. Branch is readfirstlane-uniform
//  (s_cbranch, NOT exec-masked dual execution).
//  Kept from r3/r4 (proven): 144 register-resident weight regs
//  (Wih0/Whh0/Whh1), Wih1 streamed from slot-contiguous conflict-free LDS
//  image (conflicts 7.55e7 -> 8.4e6), kc double-buffer, lgkm-only barrier,
//  log2-domain folded-bias gates, peeled prologue/epilogue, peak ~244 regs
//  (r2/r7/r8: +16 long-lived regs => spill; this round adds none).

#define B_ 2048
#define T_ 512
#define F_ 32
#define H_ 128
#define LSTR 144                 // halves per h-buffer row
#define H0SZ (8 * LSTR)          // halves per h buffer
#define W1STR 8192               // halves per wave in streamed-Wih1 LDS image

#define LOG2E 1.4426950408889634f

typedef _Float16 half8 __attribute__((ext_vector_type(8)));
typedef float float4_t __attribute__((ext_vector_type(4)));

// lgkm-only barrier: don't drain vmcnt (global x prefetch stays in flight).
#define BARRIER_LGKM() asm volatile("s_waitcnt lgkmcnt(0)\n\ts_barrier" ::: "memory")

__device__ __forceinline__ float fexp2(float x) {
  float r; asm("v_exp_f32 %0, %1" : "=v"(r) : "v"(x)); return r;
}
__device__ __forceinline__ float frcp(float x) { return __builtin_amdgcn_rcpf(x); }

__device__ __forceinline__ half8 cvt2f4(float4_t a, float4_t b) {
  half8 r;
  r[0] = (_Float16)a[0]; r[1] = (_Float16)a[1]; r[2] = (_Float16)a[2]; r[3] = (_Float16)a[3];
  r[4] = (_Float16)b[0]; r[5] = (_Float16)b[1]; r[6] = (_Float16)b[2]; r[7] = (_Float16)b[3];
  return r;
}
__device__ __forceinline__ half8 load8cvt(const float* p) {
  return cvt2f4(*(const float4_t*)p, *(const float4_t*)(p + 4));
}

__global__ __launch_bounds__(512, 2) void lstm_fused(
    const float* __restrict__ x, const float* __restrict__ Wih0,
    const float* __restrict__ Whh0, const float* __restrict__ b0,
    const float* __restrict__ Wih1, const float* __restrict__ Whh1,
    const float* __restrict__ b1, const float* __restrict__ Wfc,
    const float* __restrict__ bfc, float* __restrict__ out)
{
  __shared__ __attribute__((aligned(16))) _Float16 lds_w1[8 * W1STR];  // 131072 B
  __shared__ __attribute__((aligned(16))) _Float16 lds_h0[2 * H0SZ];   // 4608 B
  __shared__ __attribute__((aligned(16))) _Float16 lds_h1[2 * H0SZ];   // 4608 B
  __shared__ float lds_fc[8][8];

  const int tid  = threadIdx.x;
  const int w    = tid >> 6;
  const int lane = tid & 63;
  const int n    = lane & 15;
  const int q    = lane >> 4;
  const int rbase = (int)blockIdx.x * 8;
  const int rsh  = (q >> 1) * 2;            // acc rows this lane finalizes
  const int rowq = (q & 1) * 4;             // base output row
  const int colg = w * 16 + n;              // this lane's h-column
  const int aoff = (n & 7) * LSTR + q * 8;  // A-frag read offset (halves)
  // wave-uniform parity for the phase-order branch (s_cbranch, not exec mask)
  const bool wEven = (__builtin_amdgcn_readfirstlane(w & 1) == 0);

  // ---- setup: Wih0/Whh0/Whh1 -> regs; Wih1 -> slot-contiguous LDS ----
  // Image: per wave block of 8192 halves; slot (kc*4+j) stride 512 halves;
  // lane (q,n) owns halves q*128+n*8 -> each wave reads 1024 contiguous
  // bytes per ds_read_b128 slot: conflict-free.
  half8 bwih0[4], bwhh0[4][4], bwhh1[4][4];
  _Float16* w1base = lds_w1 + w * W1STR + q * 128 + n * 8;
#pragma unroll
  for (int j = 0; j < 4; ++j) {
    const int g = j * H_ + colg;            // == (j*8+w)*16+n
    bwih0[j] = load8cvt(Wih0 + g * F_ + q * 8);
#pragma unroll
    for (int kc = 0; kc < 4; ++kc) {
      bwhh0[j][kc] = load8cvt(Whh0 + g * H_ + kc * 32 + q * 8);
      bwhh1[j][kc] = load8cvt(Whh1 + g * H_ + kc * 32 + q * 8);
      *(half8*)(w1base + (kc * 4 + j) * 512) = load8cvt(Wih1 + g * H_ + kc * 32 + q * 8);
    }
  }
  // folded gate biases (log2 domain): sig(z+b)=rcp(1+2^(-z*log2e - b*log2e)),
  // tanh(z+b)=1-2*rcp(1+2^(2z*log2e + 2b*log2e))
  const float cI0 = -b0[0 * H_ + colg] * LOG2E;
  const float cF0 = -b0[1 * H_ + colg] * LOG2E;
  const float cG0 =  b0[2 * H_ + colg] * (2.0f * LOG2E);
  const float cO0 = -b0[3 * H_ + colg] * LOG2E;
  const float cI1 = -b1[0 * H_ + colg] * LOG2E;
  const float cF1 = -b1[1 * H_ + colg] * LOG2E;
  const float cG1 =  b1[2 * H_ + colg] * (2.0f * LOG2E);
  const float cO1 = -b1[3 * H_ + colg] * LOG2E;

  for (int i = tid; i < 2 * H0SZ; i += 512) { lds_h0[i] = (_Float16)0.0f; lds_h1[i] = (_Float16)0.0f; }
  __syncthreads();

  const float4_t zC = {0.f, 0.f, 0.f, 0.f};
  float c00 = 0.f, c01 = 0.f;      // layer-0 cell state (2 rows)
  float c10 = 0.f, c11 = 0.f;      // layer-1 cell state

  const float* xptr = x + (rbase + (n & 7)) * (T_ * F_) + q * 8;
  float4_t xrA = *(const float4_t*)(xptr);
  float4_t xrB = *(const float4_t*)(xptr + 4);

  // gate evaluator: 2 rows, log2-domain folded biases, writes h as f16
  auto GATES = [&](const float4_t (&acc)[4], float cI, float cF, float cG,
                   float cO, float& ca, float& cb, _Float16* dst) {
#pragma unroll
    for (int rr = 0; rr < 2; ++rr) {
      const int ri = rsh + rr;
      const float gi = frcp(1.0f + fexp2(__builtin_fmaf(acc[0][ri], -LOG2E, cI)));
      const float gf = frcp(1.0f + fexp2(__builtin_fmaf(acc[1][ri], -LOG2E, cF)));
      const float gg = 1.0f - 2.0f * frcp(1.0f + fexp2(__builtin_fmaf(acc[2][ri], 2.0f * LOG2E, cG)));
      const float go = frcp(1.0f + fexp2(__builtin_fmaf(acc[3][ri], -LOG2E, cO)));
      float& cc = rr ? cb : ca;
      cc = __builtin_fmaf(gf, cc, gi * gg);
      const float th = 1.0f - 2.0f * frcp(1.0f + fexp2(cc * (2.0f * LOG2E)));
      dst[(rowq + ri) * LSTR + colg] = (_Float16)(go * th);
    }
  };

  // layer-0 section: ih (x) + hh MFMAs (all B reg-resident), x prefetch, gates
  auto L0SEC = [&](const half8 (&ah)[4], _Float16* h0wr, int tau) {
    float4_t acc0[4];
    half8 ax = cvt2f4(xrA, xrB);
#pragma unroll
    for (int j = 0; j < 4; ++j)
      acc0[j] = __builtin_amdgcn_mfma_f32_16x16x32_f16(ax, bwih0[j], zC, 0, 0, 0);
#pragma unroll
    for (int kc = 0; kc < 4; ++kc)
#pragma unroll
      for (int j = 0; j < 4; ++j)
        acc0[j] = __builtin_amdgcn_mfma_f32_16x16x32_f16(ah[kc], bwhh0[j][kc], acc0[j], 0, 0, 0);
    const int tn = (tau + 1 < T_) ? tau + 1 : T_ - 1;     // x prefetch (clamped)
    xrA = *(const float4_t*)(xptr + tn * F_);
    xrB = *(const float4_t*)(xptr + tn * F_ + 4);
    GATES(acc0, cI0, cF0, cG0, cO0, c00, c01, h0wr);
  };

  // layer-1 section: ih streamed from LDS image (kc double-buffer) + hh (regs)
  auto L1SEC = [&](const half8 (&ah)[4], _Float16* h1rd, _Float16* h1wr) {
    float4_t acc1[4];
    half8 w1a[4], w1b[4];
#pragma unroll
    for (int j = 0; j < 4; ++j)
      w1a[j] = *(const half8*)(w1base + (0 * 4 + j) * 512);
#pragma unroll
    for (int j = 0; j < 4; ++j)
      w1b[j] = *(const half8*)(w1base + (1 * 4 + j) * 512);
#pragma unroll
    for (int j = 0; j < 4; ++j)                 // ih kc=0 (w1a dies)
      acc1[j] = __builtin_amdgcn_mfma_f32_16x16x32_f16(ah[0], w1a[j], zC, 0, 0, 0);
#pragma unroll
    for (int j = 0; j < 4; ++j)
      w1a[j] = *(const half8*)(w1base + (2 * 4 + j) * 512);
#pragma unroll
    for (int j = 0; j < 4; ++j)                 // ih kc=1 (w1b dies)
      acc1[j] = __builtin_amdgcn_mfma_f32_16x16x32_f16(ah[1], w1b[j], acc1[j], 0, 0, 0);
#pragma unroll
    for (int j = 0; j < 4; ++j)
      w1b[j] = *(const half8*)(w1base + (3 * 4 + j) * 512);
#pragma unroll
    for (int j = 0; j < 4; ++j)                 // ih kc=2
      acc1[j] = __builtin_amdgcn_mfma_f32_16x16x32_f16(ah[2], w1a[j], acc1[j], 0, 0, 0);
    half8 a1h[4];                               // h1(tau-2) (deferred load:
#pragma unroll                                  //  caps peak reg liveness)
    for (int kc = 0; kc < 4; ++kc)
      a1h[kc] = *(const half8*)(h1rd + aoff + kc * 32);
#pragma unroll
    for (int j = 0; j < 4; ++j)                 // ih kc=3
      acc1[j] = __builtin_amdgcn_mfma_f32_16x16x32_f16(ah[3], w1b[j], acc1[j], 0, 0, 0);
#pragma unroll
    for (int kc = 0; kc < 4; ++kc)              // hh (register-resident B)
#pragma unroll
      for (int j = 0; j < 4; ++j)
        acc1[j] = __builtin_amdgcn_mfma_f32_16x16x32_f16(a1h[kc], bwhh1[j][kc], acc1[j], 0, 0, 0);
    GATES(acc1, cI1, cF1, cG1, cO1, c10, c11, h1wr);
  };

  // ---- peel tau=0: layer-0 step 0 only (h_-1 = 0 -> skip hh MFMAs) ----
  {
    float4_t acc0[4];
    half8 ax = cvt2f4(xrA, xrB);
#pragma unroll
    for (int j = 0; j < 4; ++j)
      acc0[j] = __builtin_amdgcn_mfma_f32_16x16x32_f16(ax, bwih0[j], zC, 0, 0, 0);
    xrA = *(const float4_t*)(xptr + F_);            // prefetch x(1)
    xrB = *(const float4_t*)(xptr + F_ + 4);
    GATES(acc0, cI0, cF0, cG0, cO0, c00, c01, lds_h0 /* pw=0 buf */);
    BARRIER_LGKM();
  }

  // ---- main loop tau = 1..T_-1: parity-ordered sections ----
#pragma unroll 1
  for (int tau = 1; tau < T_; ++tau) {
    const int pw = tau & 1;
    _Float16* h0rd = lds_h0 + (pw ^ 1) * H0SZ;   // h0(tau-1)
    _Float16* h0wr = lds_h0 + pw * H0SZ;         // h0(tau)
    _Float16* h1rd = lds_h1 + pw * H0SZ;         // h1(tau-2)
    _Float16* h1wr = lds_h1 + (pw ^ 1) * H0SZ;   // h1(tau-1)

    half8 ah[4];                                  // h0(tau-1): shared A-frag
#pragma unroll
    for (int kc = 0; kc < 4; ++kc)
      ah[kc] = *(const half8*)(h0rd + aoff + kc * 32);

    if (wEven) {                                  // even waves: L0 -> L1
      L0SEC(ah, h0wr, tau);
      L1SEC(ah, h1rd, h1wr);
    } else {                                      // odd waves: L1 -> L0
      L1SEC(ah, h1rd, h1wr);
      L0SEC(ah, h0wr, tau);
    }
    BARRIER_LGKM();
  }

  // ---- peel tau=T_: layer-1 step T_-1 only (all waves) ----
  {
    _Float16* h0rd = lds_h0 + H0SZ;   // h0(T_-1): tau=T_-1 (pw=1) wrote buf1
    _Float16* h1rd = lds_h1;          // h1(T_-2): tau=T_-1 wrote buf0
    _Float16* h1wr = lds_h1 + H0SZ;   // h1(T_-1) -> buf1 (FC reads here)
    half8 ah[4];
#pragma unroll
    for (int kc = 0; kc < 4; ++kc)
      ah[kc] = *(const half8*)(h0rd + aoff + kc * 32);
    L1SEC(ah, h1rd, h1wr);
    asm volatile("s_waitcnt lgkmcnt(0)" ::: "memory");   // own writes visible
  }
  __syncthreads();   // h1(T_-1) visible to all waves

  // ---- FC head: out[row] = sum_c h1_last[row][c]*Wfc[c] + bfc ----
  const float wfcv = Wfc[colg];
  float p0 = (float)lds_h1[H0SZ + (rowq + rsh + 0) * LSTR + colg] * wfcv;
  float p1 = (float)lds_h1[H0SZ + (rowq + rsh + 1) * LSTR + colg] * wfcv;
#pragma unroll
  for (int m = 1; m < 16; m <<= 1) {
    p0 += __shfl_xor(p0, m);
    p1 += __shfl_xor(p1, m);
  }
  if (n == 0) {
    lds_fc[w][rowq + rsh + 0] = p0;
    lds_fc[w][rowq + rsh + 1] = p1;
  }
  __syncthreads();
  if (tid < 8) {
    float s = bfc[0];
#pragma unroll
    for (int wv = 0; wv < 8; ++wv) s += lds_fc[wv][tid];
    out[rbase + tid] = s;
  }
}

extern "C" void kernel_launch(void* const* d_in, const int* in_sizes, int n_in,
                              void* d_out, int out_size, void* d_ws, size_t ws_size,
                              hipStream_t stream) {
  const float* x    = (const float*)d_in[0];
  const float* Wih0 = (const float*)d_in[1];
  const float* Whh0 = (const float*)d_in[2];
  const float* b0   = (const float*)d_in[3];
  const float* Wih1 = (const float*)d_in[4];
  const float* Whh1 = (const float*)d_in[5];
  const float* b1   = (const float*)d_in[6];
  const float* Wfc  = (const float*)d_in[7];
  const float* bfc  = (const float*)d_in[8];
  float* outp = (float*)d_out;
  (void)d_ws; (void)ws_size;

  lstm_fused<<<B_ / 8, 512, 0, stream>>>(x, Wih0, Whh0, b0, Wih1, Whh1, b1,
                                         Wfc, bfc, outp);
}